// Round 5
// baseline (258.393 us; speedup 1.0000x reference)
//
// CAM+SE module, MI355X gfx950.
// R5: k5 retiled 64c x 128n (LDS 48 KB -> 3 blocks/CU, grid 4096, 16/CU
// queued) to hide the per-kt barrier drains via inter-block overlap (m114).
// k1/k2/k3/k4 identical to R4.
#include <hip/hip_runtime.h>
#include <cstdint>
#include <cstddef>

#define B_ 16
#define C_ 512
#define N_ 4096   // H*W
#define CH_ 64    // C/8

typedef __attribute__((ext_vector_type(8))) short short8;
typedef __attribute__((ext_vector_type(4))) float f32x4;

__device__ __forceinline__ unsigned short f2bf(float f) {
  union { float f; unsigned u; } v; v.f = f;
  unsigned r = v.u + 0x7FFFu + ((v.u >> 16) & 1u);   // RNE
  return (unsigned short)(r >> 16);
}
__device__ __forceinline__ ushort4 cvt4(float4 v) {
  ushort4 u; u.x = f2bf(v.x); u.y = f2bf(v.y); u.z = f2bf(v.z); u.w = f2bf(v.w);
  return u;
}
__device__ __forceinline__ void gload_lds16(const void* g, void* l) {
  __builtin_amdgcn_global_load_lds((__attribute__((address_space(1))) void*)g,
                                   (__attribute__((address_space(3))) void*)l,
                                   16, 0, 0);
}

// Stage one 128x64 bf16 tile pair into LDS (16 x 1KB chunks each), source
// pre-swizzled so LDS-linear dest + XOR-swizzled read match (rule #21).
__device__ __forceinline__ void stage_pair(
    const unsigned short* __restrict__ Asrc, const unsigned short* __restrict__ Bsrc,
    char* Adst, char* Bdst, int t, int ko, bool doB) {
  const int l = t & 63, wid = t >> 6;
  const int srow = l >> 3, scc = l & 7;
#pragma unroll
  for (int i = 0; i < 4; ++i) {
    const int chunk = wid * 4 + i;
    const int row = chunk * 8 + srow;
    const int cc = scc ^ (row & 7);
    gload_lds16(Asrc + (size_t)row * N_ + ko + cc * 8, Adst + chunk * 1024);
    if (doB)
      gload_lds16(Bsrc + (size_t)row * N_ + ko + cc * 8, Bdst + chunk * 1024);
  }
}
// Stage one (CPW*4*8)-row x 64-col bf16 panel, stride C_ (k5).
template <int CPW>
__device__ __forceinline__ void stage_panel_c(
    const unsigned short* __restrict__ src, char* dst, int t, int ko) {
  const int l = t & 63, wid = t >> 6;
  const int srow = l >> 3, scc = l & 7;
#pragma unroll
  for (int i = 0; i < CPW; ++i) {
    const int chunk = wid * CPW + i;
    const int row = chunk * 8 + srow;
    const int cc = scc ^ (row & 7);
    gload_lds16(src + (size_t)row * C_ + ko + cc * 8, dst + chunk * 1024);
  }
}

// One BK=64 K-step: A-op rows from Abase (wave-half wA, MF frags), B-op rows
// from Bbase (wave-half wB, NF frags). acc[m][n][r]: A-row =
// wA*MF*16 + m*16 + (l>>4)*4 + r, B-row = wB*NF*16 + n*16 + (l&15).
template <int MF, int NF>
__device__ __forceinline__ void gemm_step_t(const char* Abase, const char* Bbase,
                                            int l, int wA, int wB,
                                            f32x4 (&acc)[MF][NF]) {
#pragma unroll
  for (int ks = 0; ks < 2; ++ks) {
    short8 af[MF], bfv[NF];
#pragma unroll
    for (int m = 0; m < MF; ++m) {
      const int row = wA * (MF * 16) + m * 16 + (l & 15);
      const int ch = (ks * 4 + (l >> 4)) ^ (row & 7);
      af[m] = *(const short8*)(Abase + row * 128 + ch * 16);
    }
#pragma unroll
    for (int n = 0; n < NF; ++n) {
      const int row = wB * (NF * 16) + n * 16 + (l & 15);
      const int ch = (ks * 4 + (l >> 4)) ^ (row & 7);
      bfv[n] = *(const short8*)(Bbase + row * 128 + ch * 16);
    }
#pragma unroll
    for (int m = 0; m < MF; ++m)
#pragma unroll
      for (int n = 0; n < NF; ++n)
        acc[m][n] = __builtin_amdgcn_mfma_f32_16x16x32_bf16(af[m], bfv[n],
                                                            acc[m][n], 0, 0, 0);
  }
}

// ---------------------------------------------------------------- K1:
// x (fp32 [B][C][N]) -> qT (bf16 [B][N][C]) transposed + qbf (bf16 [B][C][N])
// + per-(b,c) partial sums over 64-col tiles for the SE mean.
__global__ __launch_bounds__(256) void k1_transpose(
    const float* __restrict__ x, unsigned short* __restrict__ qT,
    unsigned short* __restrict__ qbf, float* __restrict__ partial) {
  __shared__ alignas(16) unsigned short tile[64][72];
  const int b = blockIdx.z, ct = blockIdx.y, nt = blockIdx.x;
  const int c0 = ct * 64, n0 = nt * 64;
  const int t = threadIdx.x;
  const int r = t >> 2, q = t & 3;
  const float* xr = x + ((size_t)(b * C_ + c0 + r)) * N_ + n0;
  unsigned short* qbfr = qbf + ((size_t)(b * C_ + c0 + r)) * N_ + n0;
  float sum = 0.f;
#pragma unroll
  for (int j = 0; j < 4; ++j) {
    float4 v = *(const float4*)(xr + (q + 4 * j) * 4);
    sum += v.x + v.y + v.z + v.w;
    const int nb = (q + 4 * j) * 4;
    ushort4 u = cvt4(v);
    *(ushort4*)(qbfr + nb) = u;
    tile[nb + 0][r] = u.x;
    tile[nb + 1][r] = u.y;
    tile[nb + 2][r] = u.z;
    tile[nb + 3][r] = u.w;
  }
  sum += __shfl_xor(sum, 1);
  sum += __shfl_xor(sum, 2);
  if (q == 0) partial[((size_t)(b * C_ + c0 + r)) * 64 + nt] = sum;
  __syncthreads();
  unsigned short* qrow = qT + ((size_t)b * N_ + n0 + r) * C_ + c0 + q * 16;
  *(uint4*)(qrow)     = *(const uint4*)&tile[r][q * 16];
  *(uint4*)(qrow + 8) = *(const uint4*)&tile[r][q * 16 + 8];
}

// ---------------------------------------------------------------- K2: SE MLP
__global__ __launch_bounds__(256) void k2_se(
    const float* __restrict__ partial, const float* __restrict__ gamma,
    const float* __restrict__ W1, const float* __restrict__ b1,
    const float* __restrict__ W2, const float* __restrict__ b2,
    float* __restrict__ gse) {
  __shared__ float se_s[C_];
  __shared__ float hp[4][CH_];
  __shared__ float h_s[CH_];
  const int b = blockIdx.x, t = threadIdx.x;
  for (int c = t; c < C_; c += 256) {
    const float* p = partial + ((size_t)(b * C_ + c)) * 64;
    float s = 0.f;
#pragma unroll
    for (int i = 0; i < 64; ++i) s += p[i];
    se_s[c] = s * (1.0f / (float)N_);
  }
  __syncthreads();
  {
    const int h = t & 63, seg = t >> 6;
    float a = 0.f;
    const int cb = seg * 128;
    for (int c = cb; c < cb + 128; ++c) a += se_s[c] * W1[c * CH_ + h];
    hp[seg][h] = a;
  }
  __syncthreads();
  if (t < CH_) {
    float a = b1[t] + hp[0][t] + hp[1][t] + hp[2][t] + hp[3][t];
    h_s[t] = fmaxf(a, 0.f);
  }
  __syncthreads();
  const float g = gamma[0];
  for (int c = t; c < C_; c += 256) {
    float a = b2[c];
#pragma unroll
    for (int hh = 0; hh < CH_; ++hh) a += h_s[hh] * W2[hh * C_ + c];
    const float sig = 1.0f / (1.0f + __expf(-a));
    gse[b * C_ + c] = g * sig;
  }
}

// ---------------------------------------------------------------- K3:
// epartial[kc][b] = q q^T over K-chunk 1024. Symmetric: only 10 upper-tri
// 128^2 tiles; off-diag tiles mirror-write via a second LDS pass; diag tiles
// stage one panel. Double-buffered prefetch, 1 barrier per kt.
__global__ __launch_bounds__(256) void k3_energy(
    const unsigned short* __restrict__ qbf, float* __restrict__ ep) {
  __shared__ alignas(16) char lds[65536];   // dbuf staging, then f32 epilogue
  const int orig = blockIdx.x;
  const int wg = (orig & 7) * 80 + (orig >> 3);   // 640 = 8 x 80 bijective
  const int b = wg / 40;
  const int rem = wg % 40;
  const int kc = rem / 10;
  const int tid = rem % 10;
  int i, j;   // upper-triangle tile coords: (0,0..3),(1,1..3),(2,2..3),(3,3)
  if (tid < 4)      { i = 0; j = tid; }
  else if (tid < 7) { i = 1; j = tid - 3; }
  else if (tid < 9) { i = 2; j = tid - 5; }
  else              { i = 3; j = 3; }
  const int c0 = i * 128, d0 = j * 128;
  const bool diag = (i == j);
  const unsigned short* qb = qbf + (size_t)b * C_ * N_ + kc * 1024;
  const int t = threadIdx.x, l = t & 63, wid = t >> 6;
  const int wd = wid >> 1, wcc = wid & 1;
  f32x4 acc[4][4];   // [d-frag][c-frag]
#pragma unroll
  for (int m = 0; m < 4; ++m)
#pragma unroll
    for (int n = 0; n < 4; ++n) acc[m][n] = (f32x4){0.f, 0.f, 0.f, 0.f};
  char* A0 = lds;             char* B0 = lds + 16384;
  char* A1 = lds + 32768;     char* B1 = lds + 49152;
  const char* Bd0 = diag ? A0 : B0;   // diag: B-operand reads the A panel
  const char* Bd1 = diag ? A1 : B1;
  const unsigned short* cp = qb + (size_t)c0 * N_;   // c-panel rows
  const unsigned short* dp = qb + (size_t)d0 * N_;   // d-panel rows

  stage_pair(cp, dp, A0, B0, t, 0, !diag);
  __syncthreads();
  for (int kt2 = 0; kt2 < 8; ++kt2) {
    stage_pair(cp, dp, A1, B1, t, (2 * kt2 + 1) * 64, !diag);
    gemm_step_t<4, 4>(Bd0, A0, l, wd, wcc, acc);   // A-op = d-rows, B-op = c-rows
    __syncthreads();
    if (kt2 < 7) stage_pair(cp, dp, A0, B0, t, (2 * kt2 + 2) * 64, !diag);
    gemm_step_t<4, 4>(Bd1, A1, l, wd, wcc, acc);
    __syncthreads();
  }

  // Epilogue pass A: LDS[c][d] (float4 along d), then coalesced eb rows.
  float* Lf = (float*)lds;
  float* eb = ep + ((size_t)(kc * B_ + b)) * C_ * C_;
#pragma unroll
  for (int df = 0; df < 4; ++df)
#pragma unroll
    for (int cf = 0; cf < 4; ++cf) {
      const int c_l = wcc * 64 + cf * 16 + (l & 15);
      const int d4 = wd * 64 + df * 16 + ((l >> 4) << 2);
      *(float4*)&Lf[c_l * 128 + (d4 ^ ((c_l & 7) << 2))] =
          *(const float4*)&acc[df][cf];
    }
  __syncthreads();
#pragma unroll
  for (int jj = 0; jj < 16; ++jj) {
    const int row = jj * 8 + (t >> 5);
    const int col4 = (t & 31) * 4;
    float4 v = *(const float4*)&Lf[row * 128 + (col4 ^ ((row & 7) << 2))];
    *(float4*)&eb[(size_t)(c0 + row) * C_ + d0 + col4] = v;
  }
  if (!diag) {   // mirror block: LDS[d][c] (scalar), then coalesced rows
    __syncthreads();
#pragma unroll
    for (int df = 0; df < 4; ++df)
#pragma unroll
      for (int cf = 0; cf < 4; ++cf) {
        const int c_l = wcc * 64 + cf * 16 + (l & 15);
#pragma unroll
        for (int r = 0; r < 4; ++r) {
          const int d_l = wd * 64 + df * 16 + ((l >> 4) << 2) + r;
          Lf[d_l * 128 + (c_l ^ ((d_l & 7) << 2))] = acc[df][cf][r];
        }
      }
    __syncthreads();
#pragma unroll
    for (int jj = 0; jj < 16; ++jj) {
      const int row = jj * 8 + (t >> 5);
      const int col4 = (t & 31) * 4;
      float4 v = *(const float4*)&Lf[row * 128 + (col4 ^ ((row & 7) << 2))];
      *(float4*)&eb[(size_t)(d0 + row) * C_ + c0 + col4] = v;
    }
  }
}

// ---------------------------------------------------------------- K4:
// e = sum_kc epartial; att = exp(rowmin - e)/sum (== softmax(max-e)), bf16.
__global__ __launch_bounds__(256) void k4_softmax(const float* __restrict__ ep,
                                                  unsigned short* __restrict__ att) {
  const int t = threadIdx.x, l = t & 63, wid = t >> 6;
  const size_t row = (size_t)blockIdx.x * 4 + wid;
  f32x4 v0 = (f32x4){0.f, 0.f, 0.f, 0.f}, v1 = v0;
#pragma unroll
  for (int k = 0; k < 4; ++k) {
    const f32x4* er = (const f32x4*)(ep + ((size_t)k * B_ * C_ + row) * C_);
    v0 += er[l];
    v1 += er[64 + l];
  }
  float mn = fminf(fminf(fminf(v0[0], v0[1]), fminf(v0[2], v0[3])),
                   fminf(fminf(v1[0], v1[1]), fminf(v1[2], v1[3])));
#pragma unroll
  for (int s = 1; s < 64; s <<= 1) mn = fminf(mn, __shfl_xor(mn, s));
  float e0 = __expf(mn - v0[0]), e1 = __expf(mn - v0[1]);
  float e2 = __expf(mn - v0[2]), e3 = __expf(mn - v0[3]);
  float e4 = __expf(mn - v1[0]), e5 = __expf(mn - v1[1]);
  float e6 = __expf(mn - v1[2]), e7 = __expf(mn - v1[3]);
  float sm = ((e0 + e1) + (e2 + e3)) + ((e4 + e5) + (e6 + e7));
#pragma unroll
  for (int s = 1; s < 64; s <<= 1) sm += __shfl_xor(sm, s);
  const float inv = 1.0f / sm;
  unsigned short* ar = att + row * C_;
  ushort4 u0, u1;
  u0.x = f2bf(e0 * inv); u0.y = f2bf(e1 * inv);
  u0.z = f2bf(e2 * inv); u0.w = f2bf(e3 * inv);
  u1.x = f2bf(e4 * inv); u1.y = f2bf(e5 * inv);
  u1.z = f2bf(e6 * inv); u1.w = f2bf(e7 * inv);
  *(ushort4*)(ar + 4 * l) = u0;
  *(ushort4*)(ar + 256 + 4 * l) = u1;
}

// ---------------------------------------------------------------- K5:
// D[c][n] = att[c][:] . q[:][n]. Tile 64c x 128n, LDS 48 KB -> 3 blocks/CU.
// A-op = qT n-rows (128, acc r-dim = n), B-op = att c-rows (64).
// Dbuf prefetch; LDS-transpose epilogue: out = gse[c]*D + x, float4 rows.
__global__ __launch_bounds__(256) void k5_pv(
    const unsigned short* __restrict__ att, const unsigned short* __restrict__ qT,
    const float* __restrict__ gse, const float* __restrict__ x,
    float* __restrict__ out) {
  __shared__ alignas(16) char lds[49152];
  const int orig = blockIdx.x;
  const int wg = (orig & 7) * 512 + (orig >> 3);   // 4096 = 8 x 512 bijective
  const int b = wg >> 8;                            // 2 batches per XCD
  const int rem = wg & 255;
  const int c0 = (rem >> 5) * 64, n0 = (rem & 31) * 128;
  const int t = threadIdx.x, l = t & 63, wid = t >> 6;
  const int wn = wid >> 1, wcc = wid & 1;   // wave: n-half (64), c-half (32)
  const unsigned short* ap = att + (size_t)b * C_ * C_ + (size_t)c0 * C_;
  const unsigned short* qp = qT + (size_t)b * N_ * C_ + (size_t)n0 * C_;
  f32x4 acc[4][2];   // [n-frag][c-frag]
#pragma unroll
  for (int m = 0; m < 4; ++m)
#pragma unroll
    for (int n = 0; n < 2; ++n) acc[m][n] = (f32x4){0.f, 0.f, 0.f, 0.f};
  char* Q0 = lds;              // qT panel 128x64 = 16 KB
  char* P0 = lds + 16384;      // att panel 64x64 = 8 KB
  char* Q1 = lds + 24576;
  char* P1 = lds + 40960;

  stage_panel_c<4>(qp, Q0, t, 0);
  stage_panel_c<2>(ap, P0, t, 0);
  __syncthreads();
  for (int kt2 = 0; kt2 < 4; ++kt2) {
    stage_panel_c<4>(qp, Q1, t, (2 * kt2 + 1) * 64);
    stage_panel_c<2>(ap, P1, t, (2 * kt2 + 1) * 64);
    gemm_step_t<4, 2>(Q0, P0, l, wn, wcc, acc);
    __syncthreads();
    if (kt2 < 3) {
      stage_panel_c<4>(qp, Q0, t, (2 * kt2 + 2) * 64);
      stage_panel_c<2>(ap, P0, t, (2 * kt2 + 2) * 64);
    }
    gemm_step_t<4, 2>(Q1, P1, l, wn, wcc, acc);
    __syncthreads();
  }

  // Epilogue: LDS[c][n] (float4 along n), then fused coalesced rows.
  float* Lf = (float*)lds;
#pragma unroll
  for (int nf = 0; nf < 4; ++nf)
#pragma unroll
    for (int cf = 0; cf < 2; ++cf) {
      const int c_l = wcc * 32 + cf * 16 + (l & 15);
      const int n4 = wn * 64 + nf * 16 + ((l >> 4) << 2);
      *(float4*)&Lf[c_l * 128 + (n4 ^ ((c_l & 7) << 2))] =
          *(const float4*)&acc[nf][cf];
    }
  __syncthreads();
  const float* xb = x + (size_t)b * C_ * N_;
  float* ob = out + (size_t)b * C_ * N_;
  const float* gseb = gse + b * C_;
#pragma unroll
  for (int jj = 0; jj < 8; ++jj) {
    const int row = jj * 8 + (t >> 5);
    const int col4 = (t & 31) * 4;
    const int c = c0 + row;
    const float g = gseb[c];
    float4 v = *(const float4*)&Lf[row * 128 + (col4 ^ ((row & 7) << 2))];
    const size_t gofs = (size_t)c * N_ + n0 + col4;
    float4 xv = *(const float4*)(xb + gofs);
    float4 ov;
    ov.x = g * v.x + xv.x; ov.y = g * v.y + xv.y;
    ov.z = g * v.z + xv.z; ov.w = g * v.w + xv.w;
    *(float4*)(ob + gofs) = ov;
  }
}

// ---------------------------------------------------------------- launch
extern "C" void kernel_launch(void* const* d_in, const int* in_sizes, int n_in,
                              void* d_out, int out_size, void* d_ws, size_t ws_size,
                              hipStream_t stream) {
  (void)in_sizes; (void)n_in; (void)out_size; (void)ws_size;
  const float* x     = (const float*)d_in[0];
  const float* gamma = (const float*)d_in[1];
  const float* W1    = (const float*)d_in[2];
  const float* b1    = (const float*)d_in[3];
  const float* W2    = (const float*)d_in[4];
  const float* b2    = (const float*)d_in[5];
  float* out = (float*)d_out;
  char* ws = (char*)d_ws;

  // workspace layout (~74 MiB)
  unsigned short* qT      = (unsigned short*)(ws);                 // 64 MiB
  unsigned short* att     = (unsigned short*)(ws + 67108864);      //  8 MiB
  float*          partial = (float*)(ws + 75497472);               //  2 MiB
  float*          gse     = (float*)(ws + 77594624);               // 32 KiB
  // d_out parking (dead before k5 rewrites d_out):
  //   [0, 64 MiB):  epartial fp32 [4][B][C][C]  (k3 -> k4)
  //   [64,128 MiB): qbf bf16 [B][C][N]          (k1 -> k3)
  float*          epartial = out;
  unsigned short* qbf      = (unsigned short*)((char*)d_out + 67108864);

  k1_transpose<<<dim3(N_ / 64, C_ / 64, B_), dim3(256), 0, stream>>>(x, qT, qbf, partial);
  k2_se<<<dim3(B_), dim3(256), 0, stream>>>(partial, gamma, W1, b1, W2, b2, gse);
  k3_energy<<<dim3(640), dim3(256), 0, stream>>>(qbf, epartial);
  k4_softmax<<<dim3(B_ * C_ / 4), dim3(256), 0, stream>>>(epartial, att);
  k5_pv<<<dim3(4096), dim3(256), 0, stream>>>(att, qT, gse, x, out);
}

// Round 6
// 243.206 us; speedup vs baseline: 1.0624x; 1.0624x over previous
//
// CAM+SE module, MI355X gfx950.
// R6: revert k5 to R4's 128x128 tile/traffic (R5's retile blew up FETCH);
// k3+k5 now 512-thread 8-wave blocks on the SAME tiles -> 16 waves/CU
// (was 8) for latency hiding with identical global traffic.
#include <hip/hip_runtime.h>
#include <cstdint>
#include <cstddef>

#define B_ 16
#define C_ 512
#define N_ 4096   // H*W
#define CH_ 64    // C/8

typedef __attribute__((ext_vector_type(8))) short short8;
typedef __attribute__((ext_vector_type(4))) float f32x4;

__device__ __forceinline__ unsigned short f2bf(float f) {
  union { float f; unsigned u; } v; v.f = f;
  unsigned r = v.u + 0x7FFFu + ((v.u >> 16) & 1u);   // RNE
  return (unsigned short)(r >> 16);
}
__device__ __forceinline__ ushort4 cvt4(float4 v) {
  ushort4 u; u.x = f2bf(v.x); u.y = f2bf(v.y); u.z = f2bf(v.z); u.w = f2bf(v.w);
  return u;
}
__device__ __forceinline__ void gload_lds16(const void* g, void* l) {
  __builtin_amdgcn_global_load_lds((__attribute__((address_space(1))) void*)g,
                                   (__attribute__((address_space(3))) void*)l,
                                   16, 0, 0);
}

// Stage one 128x64 bf16 tile pair into LDS (16 x 1KB chunks each), source
// pre-swizzled so LDS-linear dest + XOR-swizzled read match (rule #21).
// CPW = chunks per wave (16 / n_waves).
template <int CPW>
__device__ __forceinline__ void stage_pair(
    const unsigned short* __restrict__ Asrc, const unsigned short* __restrict__ Bsrc,
    char* Adst, char* Bdst, int t, int ko, bool doB) {
  const int l = t & 63, wid = t >> 6;
  const int srow = l >> 3, scc = l & 7;
#pragma unroll
  for (int i = 0; i < CPW; ++i) {
    const int chunk = wid * CPW + i;
    const int row = chunk * 8 + srow;
    const int cc = scc ^ (row & 7);
    gload_lds16(Asrc + (size_t)row * N_ + ko + cc * 8, Adst + chunk * 1024);
    if (doB)
      gload_lds16(Bsrc + (size_t)row * N_ + ko + cc * 8, Bdst + chunk * 1024);
  }
}
// Same but stride C_ (k5: att / qT panels), both panels unconditional.
template <int CPW>
__device__ __forceinline__ void stage_pair_c(
    const unsigned short* __restrict__ Asrc, const unsigned short* __restrict__ Bsrc,
    char* Adst, char* Bdst, int t, int ko) {
  const int l = t & 63, wid = t >> 6;
  const int srow = l >> 3, scc = l & 7;
#pragma unroll
  for (int i = 0; i < CPW; ++i) {
    const int chunk = wid * CPW + i;
    const int row = chunk * 8 + srow;
    const int cc = scc ^ (row & 7);
    gload_lds16(Asrc + (size_t)row * C_ + ko + cc * 8, Adst + chunk * 1024);
    gload_lds16(Bsrc + (size_t)row * C_ + ko + cc * 8, Bdst + chunk * 1024);
  }
}

// One BK=64 K-step: A-op rows from Abase (wave coord wA, MF frags), B-op rows
// from Bbase (wave coord wB, NF frags). acc[m][n][r]: A-row =
// wA*MF*16 + m*16 + (l>>4)*4 + r, B-row = wB*NF*16 + n*16 + (l&15).
template <int MF, int NF>
__device__ __forceinline__ void gemm_step_t(const char* Abase, const char* Bbase,
                                            int l, int wA, int wB,
                                            f32x4 (&acc)[MF][NF]) {
#pragma unroll
  for (int ks = 0; ks < 2; ++ks) {
    short8 af[MF], bfv[NF];
#pragma unroll
    for (int m = 0; m < MF; ++m) {
      const int row = wA * (MF * 16) + m * 16 + (l & 15);
      const int ch = (ks * 4 + (l >> 4)) ^ (row & 7);
      af[m] = *(const short8*)(Abase + row * 128 + ch * 16);
    }
#pragma unroll
    for (int n = 0; n < NF; ++n) {
      const int row = wB * (NF * 16) + n * 16 + (l & 15);
      const int ch = (ks * 4 + (l >> 4)) ^ (row & 7);
      bfv[n] = *(const short8*)(Bbase + row * 128 + ch * 16);
    }
#pragma unroll
    for (int m = 0; m < MF; ++m)
#pragma unroll
      for (int n = 0; n < NF; ++n)
        acc[m][n] = __builtin_amdgcn_mfma_f32_16x16x32_bf16(af[m], bfv[n],
                                                            acc[m][n], 0, 0, 0);
  }
}

// ---------------------------------------------------------------- K1:
// x (fp32 [B][C][N]) -> qT (bf16 [B][N][C]) transposed + qbf (bf16 [B][C][N])
// + per-(b,c) partial sums over 64-col tiles for the SE mean.
__global__ __launch_bounds__(256) void k1_transpose(
    const float* __restrict__ x, unsigned short* __restrict__ qT,
    unsigned short* __restrict__ qbf, float* __restrict__ partial) {
  __shared__ alignas(16) unsigned short tile[64][72];
  const int b = blockIdx.z, ct = blockIdx.y, nt = blockIdx.x;
  const int c0 = ct * 64, n0 = nt * 64;
  const int t = threadIdx.x;
  const int r = t >> 2, q = t & 3;
  const float* xr = x + ((size_t)(b * C_ + c0 + r)) * N_ + n0;
  unsigned short* qbfr = qbf + ((size_t)(b * C_ + c0 + r)) * N_ + n0;
  float sum = 0.f;
#pragma unroll
  for (int j = 0; j < 4; ++j) {
    float4 v = *(const float4*)(xr + (q + 4 * j) * 4);
    sum += v.x + v.y + v.z + v.w;
    const int nb = (q + 4 * j) * 4;
    ushort4 u = cvt4(v);
    *(ushort4*)(qbfr + nb) = u;
    tile[nb + 0][r] = u.x;
    tile[nb + 1][r] = u.y;
    tile[nb + 2][r] = u.z;
    tile[nb + 3][r] = u.w;
  }
  sum += __shfl_xor(sum, 1);
  sum += __shfl_xor(sum, 2);
  if (q == 0) partial[((size_t)(b * C_ + c0 + r)) * 64 + nt] = sum;
  __syncthreads();
  unsigned short* qrow = qT + ((size_t)b * N_ + n0 + r) * C_ + c0 + q * 16;
  *(uint4*)(qrow)     = *(const uint4*)&tile[r][q * 16];
  *(uint4*)(qrow + 8) = *(const uint4*)&tile[r][q * 16 + 8];
}

// ---------------------------------------------------------------- K2: SE MLP
__global__ __launch_bounds__(256) void k2_se(
    const float* __restrict__ partial, const float* __restrict__ gamma,
    const float* __restrict__ W1, const float* __restrict__ b1,
    const float* __restrict__ W2, const float* __restrict__ b2,
    float* __restrict__ gse) {
  __shared__ float se_s[C_];
  __shared__ float hp[4][CH_];
  __shared__ float h_s[CH_];
  const int b = blockIdx.x, t = threadIdx.x;
  for (int c = t; c < C_; c += 256) {
    const float* p = partial + ((size_t)(b * C_ + c)) * 64;
    float s = 0.f;
#pragma unroll
    for (int i = 0; i < 64; ++i) s += p[i];
    se_s[c] = s * (1.0f / (float)N_);
  }
  __syncthreads();
  {
    const int h = t & 63, seg = t >> 6;
    float a = 0.f;
    const int cb = seg * 128;
    for (int c = cb; c < cb + 128; ++c) a += se_s[c] * W1[c * CH_ + h];
    hp[seg][h] = a;
  }
  __syncthreads();
  if (t < CH_) {
    float a = b1[t] + hp[0][t] + hp[1][t] + hp[2][t] + hp[3][t];
    h_s[t] = fmaxf(a, 0.f);
  }
  __syncthreads();
  const float g = gamma[0];
  for (int c = t; c < C_; c += 256) {
    float a = b2[c];
#pragma unroll
    for (int hh = 0; hh < CH_; ++hh) a += h_s[hh] * W2[hh * C_ + c];
    const float sig = 1.0f / (1.0f + __expf(-a));
    gse[b * C_ + c] = g * sig;
  }
}

// ---------------------------------------------------------------- K3:
// epartial[kc][b] = q q^T over K-chunk 1024. Symmetric: 10 upper-tri 128^2
// tiles, mirror-write via second LDS pass. 512 threads / 8 waves per block
// (wave = 32d x 64c quadrant), dbuf prefetch, 1 barrier per kt.
__global__ __launch_bounds__(512) void k3_energy(
    const unsigned short* __restrict__ qbf, float* __restrict__ ep) {
  __shared__ alignas(16) char lds[65536];   // dbuf staging, then f32 epilogue
  const int orig = blockIdx.x;
  const int wg = (orig & 7) * 80 + (orig >> 3);   // 640 = 8 x 80 bijective
  const int b = wg / 40;
  const int rem = wg % 40;
  const int kc = rem / 10;
  const int tid = rem % 10;
  int i, j;   // upper-triangle tile coords: (0,0..3),(1,1..3),(2,2..3),(3,3)
  if (tid < 4)      { i = 0; j = tid; }
  else if (tid < 7) { i = 1; j = tid - 3; }
  else if (tid < 9) { i = 2; j = tid - 5; }
  else              { i = 3; j = 3; }
  const int c0 = i * 128, d0 = j * 128;
  const bool diag = (i == j);
  const unsigned short* qb = qbf + (size_t)b * C_ * N_ + kc * 1024;
  const int t = threadIdx.x, l = t & 63, wid = t >> 6;
  const int wd = wid >> 1, wcc = wid & 1;   // wave: d-quarter (32), c-half (64)
  f32x4 acc[2][4];   // [d-frag][c-frag]
#pragma unroll
  for (int m = 0; m < 2; ++m)
#pragma unroll
    for (int n = 0; n < 4; ++n) acc[m][n] = (f32x4){0.f, 0.f, 0.f, 0.f};
  char* A0 = lds;             char* B0 = lds + 16384;
  char* A1 = lds + 32768;     char* B1 = lds + 49152;
  const char* Bd0 = diag ? A0 : B0;   // diag: A-operand reads the c-panel
  const char* Bd1 = diag ? A1 : B1;
  const unsigned short* cp = qb + (size_t)c0 * N_;   // c-panel rows
  const unsigned short* dp = qb + (size_t)d0 * N_;   // d-panel rows

  stage_pair<2>(cp, dp, A0, B0, t, 0, !diag);
  __syncthreads();
  for (int kt2 = 0; kt2 < 8; ++kt2) {
    stage_pair<2>(cp, dp, A1, B1, t, (2 * kt2 + 1) * 64, !diag);
    gemm_step_t<2, 4>(Bd0, A0, l, wd, wcc, acc);   // A-op = d-rows, B-op = c-rows
    __syncthreads();
    if (kt2 < 7) stage_pair<2>(cp, dp, A0, B0, t, (2 * kt2 + 2) * 64, !diag);
    gemm_step_t<2, 4>(Bd1, A1, l, wd, wcc, acc);
    __syncthreads();
  }

  // Epilogue pass A: LDS[c][d] (float4 along d), then coalesced eb rows.
  float* Lf = (float*)lds;
  float* eb = ep + ((size_t)(kc * B_ + b)) * C_ * C_;
#pragma unroll
  for (int df = 0; df < 2; ++df)
#pragma unroll
    for (int cf = 0; cf < 4; ++cf) {
      const int c_l = wcc * 64 + cf * 16 + (l & 15);
      const int d4 = wd * 32 + df * 16 + ((l >> 4) << 2);
      *(float4*)&Lf[c_l * 128 + (d4 ^ ((c_l & 7) << 2))] =
          *(const float4*)&acc[df][cf];
    }
  __syncthreads();
#pragma unroll
  for (int jj = 0; jj < 8; ++jj) {
    const int row = jj * 16 + (t >> 5);
    const int col4 = (t & 31) * 4;
    float4 v = *(const float4*)&Lf[row * 128 + (col4 ^ ((row & 7) << 2))];
    *(float4*)&eb[(size_t)(c0 + row) * C_ + d0 + col4] = v;
  }
  if (!diag) {   // mirror block: LDS[d][c] (scalar), then coalesced rows
    __syncthreads();
#pragma unroll
    for (int df = 0; df < 2; ++df)
#pragma unroll
      for (int cf = 0; cf < 4; ++cf) {
        const int c_l = wcc * 64 + cf * 16 + (l & 15);
#pragma unroll
        for (int r = 0; r < 4; ++r) {
          const int d_l = wd * 32 + df * 16 + ((l >> 4) << 2) + r;
          Lf[d_l * 128 + (c_l ^ ((d_l & 7) << 2))] = acc[df][cf][r];
        }
      }
    __syncthreads();
#pragma unroll
    for (int jj = 0; jj < 8; ++jj) {
      const int row = jj * 16 + (t >> 5);
      const int col4 = (t & 31) * 4;
      float4 v = *(const float4*)&Lf[row * 128 + (col4 ^ ((row & 7) << 2))];
      *(float4*)&eb[(size_t)(d0 + row) * C_ + c0 + col4] = v;
    }
  }
}

// ---------------------------------------------------------------- K4:
// e = sum_kc epartial; att = exp(rowmin - e)/sum (== softmax(max-e)), bf16.
__global__ __launch_bounds__(256) void k4_softmax(const float* __restrict__ ep,
                                                  unsigned short* __restrict__ att) {
  const int t = threadIdx.x, l = t & 63, wid = t >> 6;
  const size_t row = (size_t)blockIdx.x * 4 + wid;
  f32x4 v0 = (f32x4){0.f, 0.f, 0.f, 0.f}, v1 = v0;
#pragma unroll
  for (int k = 0; k < 4; ++k) {
    const f32x4* er = (const f32x4*)(ep + ((size_t)k * B_ * C_ + row) * C_);
    v0 += er[l];
    v1 += er[64 + l];
  }
  float mn = fminf(fminf(fminf(v0[0], v0[1]), fminf(v0[2], v0[3])),
                   fminf(fminf(v1[0], v1[1]), fminf(v1[2], v1[3])));
#pragma unroll
  for (int s = 1; s < 64; s <<= 1) mn = fminf(mn, __shfl_xor(mn, s));
  float e0 = __expf(mn - v0[0]), e1 = __expf(mn - v0[1]);
  float e2 = __expf(mn - v0[2]), e3 = __expf(mn - v0[3]);
  float e4 = __expf(mn - v1[0]), e5 = __expf(mn - v1[1]);
  float e6 = __expf(mn - v1[2]), e7 = __expf(mn - v1[3]);
  float sm = ((e0 + e1) + (e2 + e3)) + ((e4 + e5) + (e6 + e7));
#pragma unroll
  for (int s = 1; s < 64; s <<= 1) sm += __shfl_xor(sm, s);
  const float inv = 1.0f / sm;
  unsigned short* ar = att + row * C_;
  ushort4 u0, u1;
  u0.x = f2bf(e0 * inv); u0.y = f2bf(e1 * inv);
  u0.z = f2bf(e2 * inv); u0.w = f2bf(e3 * inv);
  u1.x = f2bf(e4 * inv); u1.y = f2bf(e5 * inv);
  u1.z = f2bf(e6 * inv); u1.w = f2bf(e7 * inv);
  *(ushort4*)(ar + 4 * l) = u0;
  *(ushort4*)(ar + 256 + 4 * l) = u1;
}

// ---------------------------------------------------------------- K5:
// D[c][n] = att[c][:] . q[:][n]. 128c x 128n tile (R4 traffic), 512 threads
// / 8 waves (wave = 32n x 64c quadrant). A-op = qT n-rows (acc r-dim = n),
// B-op = att c-rows. Dbuf prefetch; LDS-transpose fused epilogue.
__global__ __launch_bounds__(512) void k5_pv(
    const unsigned short* __restrict__ att, const unsigned short* __restrict__ qT,
    const float* __restrict__ gse, const float* __restrict__ x,
    float* __restrict__ out) {
  __shared__ alignas(16) char lds[65536];
  const int orig = blockIdx.x;
  const int wg = (orig & 7) * 256 + (orig >> 3);   // 2048 = 8 x 256 bijective
  const int b = wg >> 7;                            // 2 batches per XCD
  const int rem = wg & 127;
  const int c0 = (rem >> 5) * 128, n0 = (rem & 31) * 128;
  const int t = threadIdx.x, l = t & 63, wid = t >> 6;
  const int wn = wid >> 1, wcc = wid & 1;   // wave: n-quarter (32), c-half (64)
  const unsigned short* ap = att + (size_t)b * C_ * C_ + (size_t)c0 * C_;
  const unsigned short* qp = qT + (size_t)b * N_ * C_ + (size_t)n0 * C_;
  f32x4 acc[2][4];   // [n-frag][c-frag]
#pragma unroll
  for (int m = 0; m < 2; ++m)
#pragma unroll
    for (int n = 0; n < 4; ++n) acc[m][n] = (f32x4){0.f, 0.f, 0.f, 0.f};
  char* A0 = lds;             char* B0 = lds + 16384;
  char* A1 = lds + 32768;     char* B1 = lds + 49152;

  stage_pair_c<2>(ap, qp, A0, B0, t, 0);
  __syncthreads();
  for (int kt2 = 0; kt2 < 4; ++kt2) {
    stage_pair_c<2>(ap, qp, A1, B1, t, (2 * kt2 + 1) * 64);
    gemm_step_t<2, 4>(B0, A0, l, wn, wcc, acc);   // A-op = qT n-rows, B-op = att c-rows
    __syncthreads();
    if (kt2 < 3) stage_pair_c<2>(ap, qp, A0, B0, t, (2 * kt2 + 2) * 64);
    gemm_step_t<2, 4>(B1, A1, l, wn, wcc, acc);
    __syncthreads();
  }

  // Epilogue: LDS[c][n] (float4 along n), then fused coalesced rows.
  float* Lf = (float*)lds;
#pragma unroll
  for (int nf = 0; nf < 2; ++nf)
#pragma unroll
    for (int cf = 0; cf < 4; ++cf) {
      const int c_l = wcc * 64 + cf * 16 + (l & 15);
      const int n4 = wn * 32 + nf * 16 + ((l >> 4) << 2);
      *(float4*)&Lf[c_l * 128 + (n4 ^ ((c_l & 7) << 2))] =
          *(const float4*)&acc[nf][cf];
    }
  __syncthreads();
  const float* xb = x + (size_t)b * C_ * N_;
  float* ob = out + (size_t)b * C_ * N_;
  const float* gseb = gse + b * C_;
#pragma unroll
  for (int jj = 0; jj < 8; ++jj) {
    const int row = jj * 16 + (t >> 5);
    const int col4 = (t & 31) * 4;
    const int c = c0 + row;
    const float g = gseb[c];
    float4 v = *(const float4*)&Lf[row * 128 + (col4 ^ ((row & 7) << 2))];
    const size_t gofs = (size_t)c * N_ + n0 + col4;
    float4 xv = *(const float4*)(xb + gofs);
    float4 ov;
    ov.x = g * v.x + xv.x; ov.y = g * v.y + xv.y;
    ov.z = g * v.z + xv.z; ov.w = g * v.w + xv.w;
    *(float4*)(ob + gofs) = ov;
  }
}

// ---------------------------------------------------------------- launch
extern "C" void kernel_launch(void* const* d_in, const int* in_sizes, int n_in,
                              void* d_out, int out_size, void* d_ws, size_t ws_size,
                              hipStream_t stream) {
  (void)in_sizes; (void)n_in; (void)out_size; (void)ws_size;
  const float* x     = (const float*)d_in[0];
  const float* gamma = (const float*)d_in[1];
  const float* W1    = (const float*)d_in[2];
  const float* b1    = (const float*)d_in[3];
  const float* W2    = (const float*)d_in[4];
  const float* b2    = (const float*)d_in[5];
  float* out = (float*)d_out;
  char* ws = (char*)d_ws;

  // workspace layout (~74 MiB)
  unsigned short* qT      = (unsigned short*)(ws);                 // 64 MiB
  unsigned short* att     = (unsigned short*)(ws + 67108864);      //  8 MiB
  float*          partial = (float*)(ws + 75497472);               //  2 MiB
  float*          gse     = (float*)(ws + 77594624);               // 32 KiB
  // d_out parking (dead before k5 rewrites d_out):
  //   [0, 64 MiB):  epartial fp32 [4][B][C][C]  (k3 -> k4)
  //   [64,128 MiB): qbf bf16 [B][C][N]          (k1 -> k3)
  float*          epartial = out;
  unsigned short* qbf      = (unsigned short*)((char*)d_out + 67108864);

  k1_transpose<<<dim3(N_ / 64, C_ / 64, B_), dim3(256), 0, stream>>>(x, qT, qbf, partial);
  k2_se<<<dim3(B_), dim3(256), 0, stream>>>(partial, gamma, W1, b1, W2, b2, gse);
  k3_energy<<<dim3(640), dim3(512), 0, stream>>>(qbf, epartial);
  k4_softmax<<<dim3(B_ * C_ / 4), dim3(256), 0, stream>>>(epartial, att);
  k5_pv<<<dim3(2048), dim3(512), 0, stream>>>(att, qT, gse, x, out);
}